// Round 17
// baseline (223.571 us; speedup 1.0000x reference)
//
#include <hip/hip_runtime.h>

// FeatureDecorr: group whitening via Newton-Schulz isqrt of 16x16 group covariance.
// x: (32, 256, 56, 56) fp32. Group g = c % 16; plane-set p = (n, c/16).
//
// CONFIG: all-caching (R12-best, 92us) + stats occupancy doubled:
//   fd_stats  __launch_bounds__(256,8), split x8 (4096 blocks) -> 8 waves/SIMD
//   fd_whiten caching loads (x L3-warm from stats) + NT stores (unchanged control)
//
//  1) fd_stats:  direct 16-stream float4 caching loads; 4-wave split triangle.
//  2) fd_reduce: 152 blocks, each sums one contiguous 4096-float partial row.
//  3) fd_newton: NS-10 on 16x16 in LDS.
//  4) fd_whiten: wave owns 4 output planes; caching loads + NT stores.

constexpr int kC    = 256;
constexpr int kHW   = 3136;   // 56*56
constexpr int kP    = 512;    // N * (C/G) plane-sets
constexpr int kAcc  = 152;    // 16 sums + 136 upper-tri products
constexpr float kEps = 1e-5f;
constexpr int kNsIter = 10;
constexpr int kSplit  = 4;    // whiten spatial split (control)
constexpr int kChunk  = 196;  // whiten float4 positions per block
constexpr int kSSplit = 8;    // stats spatial split (this round's variable)
constexpr int kSChunk = 98;   // stats float4 positions per block (784/8)
constexpr int kNB   = kP * kSSplit;  // 4096 stats blocks

typedef float floatx4 __attribute__((ext_vector_type(4)));

__device__ __host__ constexpr int triidx(int j, int k) {  // j<=k
  return j * 16 - (j * (j - 1)) / 2 + (k - j);
}

// ---- DPP wave64 float sum (VALU-rate) ----
template <int Ctrl, int RowMask>
__device__ __forceinline__ float dpp_fadd(float x) {
  int perm = __builtin_amdgcn_update_dpp(0, __float_as_int(x), Ctrl, RowMask, 0xf, true);
  return x + __int_as_float(perm);
}
__device__ __forceinline__ float wave_sum64(float x) {
  x = dpp_fadd<0xB1, 0xF>(x);   // quad_perm xor1
  x = dpp_fadd<0x4E, 0xF>(x);   // quad_perm xor2
  x = dpp_fadd<0x124, 0xF>(x);  // row_ror:4
  x = dpp_fadd<0x128, 0xF>(x);  // row_ror:8
  x = dpp_fadd<0x142, 0xA>(x);  // row_bcast15
  x = dpp_fadd<0x143, 0xC>(x);  // row_bcast31 -> lane 63 = full sum
  return x;
}

// ---------------- kernel 1: statistics (direct caching loads, 8 waves/SIMD) ----------------
template <int R0, int R1, int R2, int R3>
struct RowSet {
  static constexpr int O0 = 0;
  static constexpr int O1 = O0 + (16 - R0);
  static constexpr int O2 = O1 + (16 - R1);
  static constexpr int O3 = O2 + (16 - R2);
};

template <int R0, int R1, int R2, int R3, int S0>
__device__ __forceinline__ void accum_direct(const float4* __restrict__ xq, int lane,
                                             float* __restrict__ acc) {
  using RS = RowSet<R0, R1, R2, R3>;
  for (int pos = lane; pos < kSChunk; pos += 64) {
    float4 v[16];
#pragma unroll
    for (int c = 0; c < 16; ++c) v[c] = xq[c * (kHW / 4) + pos];  // 16 indep streams
#pragma unroll
    for (int c = 0; c < 4; ++c) {
      const float4 u = v[S0 + c];
      acc[34 + c] += (u.x + u.y) + (u.z + u.w);
    }
#define ROWP(R, O)                                                             \
  _Pragma("unroll") for (int k = R; k < 16; ++k) {                             \
    acc[(O) + k - (R)] +=                                                      \
        v[R].x * v[k].x + v[R].y * v[k].y + v[R].z * v[k].z + v[R].w * v[k].w; \
  }
    ROWP(R0, RS::O0) ROWP(R1, RS::O1) ROWP(R2, RS::O2) ROWP(R3, RS::O3)
#undef ROWP
  }
}

template <int R0, int R1, int R2, int R3, int S0>
__device__ __forceinline__ void write_acc(float* __restrict__ pT, int blk, int lane,
                                          const float* __restrict__ acc) {
  using RS = RowSet<R0, R1, R2, R3>;
#pragma unroll
  for (int k = R0; k < 16; ++k) {
    float r = wave_sum64(acc[RS::O0 + k - R0]);
    if (lane == 63) pT[(size_t)(16 + triidx(R0, k)) * kNB + blk] = r;
  }
#pragma unroll
  for (int k = R1; k < 16; ++k) {
    float r = wave_sum64(acc[RS::O1 + k - R1]);
    if (lane == 63) pT[(size_t)(16 + triidx(R1, k)) * kNB + blk] = r;
  }
#pragma unroll
  for (int k = R2; k < 16; ++k) {
    float r = wave_sum64(acc[RS::O2 + k - R2]);
    if (lane == 63) pT[(size_t)(16 + triidx(R2, k)) * kNB + blk] = r;
  }
#pragma unroll
  for (int k = R3; k < 16; ++k) {
    float r = wave_sum64(acc[RS::O3 + k - R3]);
    if (lane == 63) pT[(size_t)(16 + triidx(R3, k)) * kNB + blk] = r;
  }
#pragma unroll
  for (int c = 0; c < 4; ++c) {
    float r = wave_sum64(acc[34 + c]);
    if (lane == 63) pT[(size_t)(S0 + c) * kNB + blk] = r;
  }
}

__global__ __launch_bounds__(256, 8) void fd_stats(const float* __restrict__ x,
                                                   float* __restrict__ pT) {
  const int blk = blockIdx.x;
  const int p = blk >> 3, s = blk & (kSSplit - 1);
  const int n = p >> 4, c1 = p & 15;
  const int t = threadIdx.x;
  const int w = __builtin_amdgcn_readfirstlane(t >> 6);
  const int lane = t & 63;

  const float4* xq = reinterpret_cast<const float4*>(x) +
                     (size_t)(n * kC + c1 * 16) * (kHW / 4) + s * kSChunk;

  float acc[38];
#pragma unroll
  for (int a = 0; a < 38; ++a) acc[a] = 0.f;

  switch (w) {
    case 0:  accum_direct<0, 1, 14, 15, 0 >(xq, lane, acc); break;
    case 1:  accum_direct<2, 3, 12, 13, 4 >(xq, lane, acc); break;
    case 2:  accum_direct<4, 5, 10, 11, 8 >(xq, lane, acc); break;
    default: accum_direct<6, 7, 8,  9,  12>(xq, lane, acc); break;
  }
  switch (w) {
    case 0:  write_acc<0, 1, 14, 15, 0 >(pT, blk, lane, acc); break;
    case 1:  write_acc<2, 3, 12, 13, 4 >(pT, blk, lane, acc); break;
    case 2:  write_acc<4, 5, 10, 11, 8 >(pT, blk, lane, acc); break;
    default: write_acc<6, 7, 8,  9,  12>(pT, blk, lane, acc); break;
  }
}

// ---------- kernel 2: parallel partial reduce (one block per accumulator) ----------
__global__ __launch_bounds__(256) void fd_reduce(const float* __restrict__ pT,
                                                 float* __restrict__ statsg) {
  __shared__ float wbuf[4];
  const int a = blockIdx.x;
  const int t = threadIdx.x, lane = t & 63, w = t >> 6;
  const float4* row = reinterpret_cast<const float4*>(pT + (size_t)a * kNB);
  float4 v0 = row[t], v1 = row[t + 256], v2 = row[t + 512], v3 = row[t + 768];
  float sum = (((v0.x + v0.y) + (v0.z + v0.w)) + ((v1.x + v1.y) + (v1.z + v1.w))) +
              (((v2.x + v2.y) + (v2.z + v2.w)) + ((v3.x + v3.y) + (v3.z + v3.w)));
  float r = wave_sum64(sum);
  if (lane == 63) wbuf[w] = r;
  __syncthreads();
  if (t == 0) statsg[a] = (wbuf[0] + wbuf[1]) + (wbuf[2] + wbuf[3]);
}

// -------- kernel 3: Newton-Schulz isqrt (single block; stats pre-reduced) --------
__global__ __launch_bounds__(256) void fd_newton(const float* __restrict__ statsg,
                                                 float* __restrict__ params) {
  __shared__ float stats[kAcc];
  __shared__ float meanv[16];
  __shared__ float Yb[2][256];
  __shared__ float Zb[2][256];
  __shared__ float Tm[256];
  __shared__ float redb[4];
  __shared__ float snorm;
  const int t = threadIdx.x;

  if (t < kAcc) stats[t] = statsg[t];
  __syncthreads();

  constexpr float invM = 1.0f / (float)(kP * kHW);
  if (t < 16) meanv[t] = stats[t] * invM;
  __syncthreads();

  const int i = t >> 4, j = t & 15;
  const int a = i < j ? i : j, b = i < j ? j : i;
  float cij = stats[16 + triidx(a, b)] * invM - meanv[i] * meanv[j];
  if (i == j) cij += kEps;

  float r = wave_sum64(cij * cij);
  if ((t & 63) == 63) redb[t >> 6] = r;
  __syncthreads();
  if (t == 0) snorm = sqrtf((redb[0] + redb[1]) + (redb[2] + redb[3]));
  __syncthreads();

  Yb[0][t] = cij * (1.0f / snorm);
  Zb[0][t] = (i == j) ? 1.0f : 0.0f;
  __syncthreads();

  int cur = 0;
  for (int it = 0; it < kNsIter; ++it) {
    float acc = 0.f;
#pragma unroll
    for (int k = 0; k < 16; ++k) acc += Zb[cur][i * 16 + k] * Yb[cur][k * 16 + j];
    Tm[t] = ((i == j) ? 1.5f : 0.0f) - 0.5f * acc;
    __syncthreads();
    float y = 0.f, z = 0.f;
#pragma unroll
    for (int k = 0; k < 16; ++k) {
      y += Yb[cur][i * 16 + k] * Tm[k * 16 + j];
      z += Tm[i * 16 + k] * Zb[cur][k * 16 + j];
    }
    Yb[cur ^ 1][t] = y;
    Zb[cur ^ 1][t] = z;
    cur ^= 1;
    __syncthreads();
  }

  const float D = Zb[cur][t] / sqrtf(snorm);
  params[t] = D;
  Tm[t] = D * meanv[j];
  __syncthreads();
  if (t < 16) {
    float o = 0.f;
#pragma unroll
    for (int k = 0; k < 16; ++k) o += Tm[t * 16 + k];
    params[256 + t] = o;  // offset[g] = sum_j D[g][j]*mean[j]
  }
}

// --------------- kernel 4: whitening (caching loads + NT stores; control) ---------------
__global__ __launch_bounds__(256, 4) void fd_whiten(const float* __restrict__ x,
                                                    const float* __restrict__ weight,
                                                    const float* __restrict__ bias,
                                                    const float* __restrict__ params,
                                                    float* __restrict__ out) {
  const int blk = blockIdx.x;
  const int p = blk >> 2, s = blk & (kSplit - 1);
  const int n = p >> 4, c1 = p & 15;
  const int t = threadIdx.x;
  const int w    = __builtin_amdgcn_readfirstlane(t >> 6);
  const int lane = t & 63;
  const int g0   = 4 * w;

  const float* base  = x   + (size_t)(n * kC + c1 * 16) * kHW;
  float*       obase = out + (size_t)(n * kC + c1 * 16) * kHW;

  float d[4][16];
#pragma unroll
  for (int gg = 0; gg < 4; ++gg)
#pragma unroll
    for (int j = 0; j < 16; ++j)
      d[gg][j] = params[(g0 + gg) * 16 + j];

  float wv[4], sv[4];
#pragma unroll
  for (int gg = 0; gg < 4; ++gg) {
    const int g  = g0 + gg;
    const int ch = c1 * 16 + g;
    wv[gg] = weight[ch];
    sv[gg] = bias[ch] - params[256 + g] * wv[gg];  // bias - w * (D@mean)
  }

  for (int lp = lane; lp < kChunk; lp += 64) {
    const int pos = s * kChunk + lp;
    float4 acc0 = make_float4(0.f, 0.f, 0.f, 0.f);
    float4 acc1 = acc0, acc2 = acc0, acc3 = acc0;
#pragma unroll
    for (int j = 0; j < 16; ++j) {
      const float4 v = reinterpret_cast<const float4*>(base + j * kHW)[pos];
#define ACC(A, dd) A.x += (dd) * v.x; A.y += (dd) * v.y; A.z += (dd) * v.z; A.w += (dd) * v.w;
      ACC(acc0, d[0][j]); ACC(acc1, d[1][j]); ACC(acc2, d[2][j]); ACC(acc3, d[3][j]);
#undef ACC
    }
#define EMIT(A, gg)                                                          \
    {                                                                        \
      floatx4 o;                                                             \
      o.x = A.x * wv[gg] + sv[gg]; o.y = A.y * wv[gg] + sv[gg];              \
      o.z = A.z * wv[gg] + sv[gg]; o.w = A.w * wv[gg] + sv[gg];              \
      __builtin_nontemporal_store(                                           \
          o, reinterpret_cast<floatx4*>(obase + (g0 + gg) * kHW) + pos);     \
    }
    EMIT(acc0, 0) EMIT(acc1, 1) EMIT(acc2, 2) EMIT(acc3, 3)
#undef EMIT
  }
}

extern "C" void kernel_launch(void* const* d_in, const int* in_sizes, int n_in,
                              void* d_out, int out_size, void* d_ws, size_t ws_size,
                              hipStream_t stream) {
  const float* x      = (const float*)d_in[0];
  const float* weight = (const float*)d_in[1];
  const float* bias   = (const float*)d_in[2];
  float* out = (float*)d_out;

  float* wsf      = (float*)d_ws;
  float* partials = wsf;                             // kAcc * kNB floats (transposed)
  float* statsg   = wsf + (size_t)kAcc * kNB;        // 152 reduced stats
  float* params   = statsg + kAcc;                   // 256 (D) + 16 (offset)

  fd_stats <<<kNB,  256, 0, stream>>>(x, partials);
  fd_reduce<<<kAcc, 256, 0, stream>>>(partials, statsg);
  fd_newton<<<1,    256, 0, stream>>>(statsg, params);
  fd_whiten<<<kP * kSplit, 256, 0, stream>>>(x, weight, bias, params, out);
}

// Round 18
// 90.675 us; speedup vs baseline: 2.4656x; 2.4656x over previous
//
#include <hip/hip_runtime.h>

// FeatureDecorr: group whitening via Newton-Schulz isqrt of 16x16 group covariance.
// x: (32, 256, 56, 56) fp32. Group g = c % 16; plane-set p = (n, c/16).
//
// MODEL (R5-R17): the harness's 392MB fill writeback saturates HBM for ~60us at
// the start of every replay and evicts L3 (392>256MB); fd_stats (first, needs
// 98MB of x) is drain-co-limited at ~60us for ANY kernel structure (6 variants
// measured 60+-5). Whiten reads x L3-warm (stats' caching loads re-warm it) at
// ~7 TB/s. Constrained floor ~= 60 + 6 + ~20 = ~86us.
//
//  1) fd_stats:  direct 16-stream float4 caching loads (measured-best R10 form);
//                4-wave split triangle, 38 VGPR accums, launch_bounds(256,4).
//  2) fd_reduce: 152 blocks, each sums one contiguous 2048-float partial row.
//  3) fd_newton: NS-10 on 16x16 in LDS.
//  4) fd_whiten: wave owns 4 output planes; caching loads + NT stores;
//                launch_bounds(256,8) (VGPR=36 fits 64-budget) for write-overlap TLP.

constexpr int kC    = 256;
constexpr int kHW   = 3136;   // 56*56
constexpr int kP    = 512;    // N * (C/G) plane-sets
constexpr int kAcc  = 152;    // 16 sums + 136 upper-tri products
constexpr float kEps = 1e-5f;
constexpr int kNsIter = 10;
constexpr int kSplit = 4;     // spatial split (stats & whiten)
constexpr int kChunk = 196;   // float4 positions per block-quarter
constexpr int kNB   = kP * 4; // 2048 stats blocks

typedef float floatx4 __attribute__((ext_vector_type(4)));

__device__ __host__ constexpr int triidx(int j, int k) {  // j<=k
  return j * 16 - (j * (j - 1)) / 2 + (k - j);
}

// ---- DPP wave64 float sum (VALU-rate) ----
template <int Ctrl, int RowMask>
__device__ __forceinline__ float dpp_fadd(float x) {
  int perm = __builtin_amdgcn_update_dpp(0, __float_as_int(x), Ctrl, RowMask, 0xf, true);
  return x + __int_as_float(perm);
}
__device__ __forceinline__ float wave_sum64(float x) {
  x = dpp_fadd<0xB1, 0xF>(x);   // quad_perm xor1
  x = dpp_fadd<0x4E, 0xF>(x);   // quad_perm xor2
  x = dpp_fadd<0x124, 0xF>(x);  // row_ror:4
  x = dpp_fadd<0x128, 0xF>(x);  // row_ror:8
  x = dpp_fadd<0x142, 0xA>(x);  // row_bcast15
  x = dpp_fadd<0x143, 0xC>(x);  // row_bcast31 -> lane 63 = full sum
  return x;
}

// ---------------- kernel 1: statistics (direct caching loads, wave-split triangle) ----------------
template <int R0, int R1, int R2, int R3>
struct RowSet {
  static constexpr int O0 = 0;
  static constexpr int O1 = O0 + (16 - R0);
  static constexpr int O2 = O1 + (16 - R1);
  static constexpr int O3 = O2 + (16 - R2);
};

template <int R0, int R1, int R2, int R3, int S0>
__device__ __forceinline__ void accum_direct(const float4* __restrict__ xq, int lane,
                                             float* __restrict__ acc) {
  using RS = RowSet<R0, R1, R2, R3>;
  for (int pos = lane; pos < kChunk; pos += 64) {
    float4 v[16];
#pragma unroll
    for (int c = 0; c < 16; ++c) v[c] = xq[c * (kHW / 4) + pos];  // 16 indep streams
#pragma unroll
    for (int c = 0; c < 4; ++c) {
      const float4 u = v[S0 + c];
      acc[34 + c] += (u.x + u.y) + (u.z + u.w);
    }
#define ROWP(R, O)                                                             \
  _Pragma("unroll") for (int k = R; k < 16; ++k) {                             \
    acc[(O) + k - (R)] +=                                                      \
        v[R].x * v[k].x + v[R].y * v[k].y + v[R].z * v[k].z + v[R].w * v[k].w; \
  }
    ROWP(R0, RS::O0) ROWP(R1, RS::O1) ROWP(R2, RS::O2) ROWP(R3, RS::O3)
#undef ROWP
  }
}

template <int R0, int R1, int R2, int R3, int S0>
__device__ __forceinline__ void write_acc(float* __restrict__ pT, int blk, int lane,
                                          const float* __restrict__ acc) {
  using RS = RowSet<R0, R1, R2, R3>;
#pragma unroll
  for (int k = R0; k < 16; ++k) {
    float r = wave_sum64(acc[RS::O0 + k - R0]);
    if (lane == 63) pT[(size_t)(16 + triidx(R0, k)) * kNB + blk] = r;
  }
#pragma unroll
  for (int k = R1; k < 16; ++k) {
    float r = wave_sum64(acc[RS::O1 + k - R1]);
    if (lane == 63) pT[(size_t)(16 + triidx(R1, k)) * kNB + blk] = r;
  }
#pragma unroll
  for (int k = R2; k < 16; ++k) {
    float r = wave_sum64(acc[RS::O2 + k - R2]);
    if (lane == 63) pT[(size_t)(16 + triidx(R2, k)) * kNB + blk] = r;
  }
#pragma unroll
  for (int k = R3; k < 16; ++k) {
    float r = wave_sum64(acc[RS::O3 + k - R3]);
    if (lane == 63) pT[(size_t)(16 + triidx(R3, k)) * kNB + blk] = r;
  }
#pragma unroll
  for (int c = 0; c < 4; ++c) {
    float r = wave_sum64(acc[34 + c]);
    if (lane == 63) pT[(size_t)(S0 + c) * kNB + blk] = r;
  }
}

__global__ __launch_bounds__(256, 4) void fd_stats(const float* __restrict__ x,
                                                   float* __restrict__ pT) {
  const int blk = blockIdx.x;
  const int p = blk >> 2, s = blk & 3;
  const int n = p >> 4, c1 = p & 15;
  const int t = threadIdx.x;
  const int w = __builtin_amdgcn_readfirstlane(t >> 6);
  const int lane = t & 63;

  const float4* xq = reinterpret_cast<const float4*>(x) +
                     (size_t)(n * kC + c1 * 16) * (kHW / 4) + s * kChunk;

  float acc[38];
#pragma unroll
  for (int a = 0; a < 38; ++a) acc[a] = 0.f;

  switch (w) {
    case 0:  accum_direct<0, 1, 14, 15, 0 >(xq, lane, acc); break;
    case 1:  accum_direct<2, 3, 12, 13, 4 >(xq, lane, acc); break;
    case 2:  accum_direct<4, 5, 10, 11, 8 >(xq, lane, acc); break;
    default: accum_direct<6, 7, 8,  9,  12>(xq, lane, acc); break;
  }
  switch (w) {
    case 0:  write_acc<0, 1, 14, 15, 0 >(pT, blk, lane, acc); break;
    case 1:  write_acc<2, 3, 12, 13, 4 >(pT, blk, lane, acc); break;
    case 2:  write_acc<4, 5, 10, 11, 8 >(pT, blk, lane, acc); break;
    default: write_acc<6, 7, 8,  9,  12>(pT, blk, lane, acc); break;
  }
}

// ---------- kernel 2: parallel partial reduce (one block per accumulator) ----------
__global__ __launch_bounds__(256) void fd_reduce(const float* __restrict__ pT,
                                                 float* __restrict__ statsg) {
  __shared__ float wbuf[4];
  const int a = blockIdx.x;
  const int t = threadIdx.x, lane = t & 63, w = t >> 6;
  const float4* row = reinterpret_cast<const float4*>(pT + (size_t)a * kNB);
  float4 v0 = row[t], v1 = row[t + 256];
  float sum = ((v0.x + v0.y) + (v0.z + v0.w)) + ((v1.x + v1.y) + (v1.z + v1.w));
  float r = wave_sum64(sum);
  if (lane == 63) wbuf[w] = r;
  __syncthreads();
  if (t == 0) statsg[a] = (wbuf[0] + wbuf[1]) + (wbuf[2] + wbuf[3]);
}

// -------- kernel 3: Newton-Schulz isqrt (single block; stats pre-reduced) --------
__global__ __launch_bounds__(256) void fd_newton(const float* __restrict__ statsg,
                                                 float* __restrict__ params) {
  __shared__ float stats[kAcc];
  __shared__ float meanv[16];
  __shared__ float Yb[2][256];
  __shared__ float Zb[2][256];
  __shared__ float Tm[256];
  __shared__ float redb[4];
  __shared__ float snorm;
  const int t = threadIdx.x;

  if (t < kAcc) stats[t] = statsg[t];
  __syncthreads();

  constexpr float invM = 1.0f / (float)(kP * kHW);
  if (t < 16) meanv[t] = stats[t] * invM;
  __syncthreads();

  const int i = t >> 4, j = t & 15;
  const int a = i < j ? i : j, b = i < j ? j : i;
  float cij = stats[16 + triidx(a, b)] * invM - meanv[i] * meanv[j];
  if (i == j) cij += kEps;

  float r = wave_sum64(cij * cij);
  if ((t & 63) == 63) redb[t >> 6] = r;
  __syncthreads();
  if (t == 0) snorm = sqrtf((redb[0] + redb[1]) + (redb[2] + redb[3]));
  __syncthreads();

  Yb[0][t] = cij * (1.0f / snorm);
  Zb[0][t] = (i == j) ? 1.0f : 0.0f;
  __syncthreads();

  int cur = 0;
  for (int it = 0; it < kNsIter; ++it) {
    float acc = 0.f;
#pragma unroll
    for (int k = 0; k < 16; ++k) acc += Zb[cur][i * 16 + k] * Yb[cur][k * 16 + j];
    Tm[t] = ((i == j) ? 1.5f : 0.0f) - 0.5f * acc;
    __syncthreads();
    float y = 0.f, z = 0.f;
#pragma unroll
    for (int k = 0; k < 16; ++k) {
      y += Yb[cur][i * 16 + k] * Tm[k * 16 + j];
      z += Tm[i * 16 + k] * Zb[cur][k * 16 + j];
    }
    Yb[cur ^ 1][t] = y;
    Zb[cur ^ 1][t] = z;
    cur ^= 1;
    __syncthreads();
  }

  const float D = Zb[cur][t] / sqrtf(snorm);
  params[t] = D;
  Tm[t] = D * meanv[j];
  __syncthreads();
  if (t < 16) {
    float o = 0.f;
#pragma unroll
    for (int k = 0; k < 16; ++k) o += Tm[t * 16 + k];
    params[256 + t] = o;  // offset[g] = sum_j D[g][j]*mean[j]
  }
}

// --------------- kernel 4: whitening (caching loads + NT stores, 8 waves/EU) ---------------
__global__ __launch_bounds__(256, 8) void fd_whiten(const float* __restrict__ x,
                                                    const float* __restrict__ weight,
                                                    const float* __restrict__ bias,
                                                    const float* __restrict__ params,
                                                    float* __restrict__ out) {
  const int blk = blockIdx.x;
  const int p = blk >> 2, s = blk & (kSplit - 1);
  const int n = p >> 4, c1 = p & 15;
  const int t = threadIdx.x;
  const int w    = __builtin_amdgcn_readfirstlane(t >> 6);
  const int lane = t & 63;
  const int g0   = 4 * w;

  const float* base  = x   + (size_t)(n * kC + c1 * 16) * kHW;
  float*       obase = out + (size_t)(n * kC + c1 * 16) * kHW;

  float d[4][16];
#pragma unroll
  for (int gg = 0; gg < 4; ++gg)
#pragma unroll
    for (int j = 0; j < 16; ++j)
      d[gg][j] = params[(g0 + gg) * 16 + j];

  float wv[4], sv[4];
#pragma unroll
  for (int gg = 0; gg < 4; ++gg) {
    const int g  = g0 + gg;
    const int ch = c1 * 16 + g;
    wv[gg] = weight[ch];
    sv[gg] = bias[ch] - params[256 + g] * wv[gg];  // bias - w * (D@mean)
  }

  for (int lp = lane; lp < kChunk; lp += 64) {
    const int pos = s * kChunk + lp;
    float4 acc0 = make_float4(0.f, 0.f, 0.f, 0.f);
    float4 acc1 = acc0, acc2 = acc0, acc3 = acc0;
#pragma unroll
    for (int j = 0; j < 16; ++j) {
      const float4 v = reinterpret_cast<const float4*>(base + j * kHW)[pos];
#define ACC(A, dd) A.x += (dd) * v.x; A.y += (dd) * v.y; A.z += (dd) * v.z; A.w += (dd) * v.w;
      ACC(acc0, d[0][j]); ACC(acc1, d[1][j]); ACC(acc2, d[2][j]); ACC(acc3, d[3][j]);
#undef ACC
    }
#define EMIT(A, gg)                                                          \
    {                                                                        \
      floatx4 o;                                                             \
      o.x = A.x * wv[gg] + sv[gg]; o.y = A.y * wv[gg] + sv[gg];              \
      o.z = A.z * wv[gg] + sv[gg]; o.w = A.w * wv[gg] + sv[gg];              \
      __builtin_nontemporal_store(                                           \
          o, reinterpret_cast<floatx4*>(obase + (g0 + gg) * kHW) + pos);     \
    }
    EMIT(acc0, 0) EMIT(acc1, 1) EMIT(acc2, 2) EMIT(acc3, 3)
#undef EMIT
  }
}

extern "C" void kernel_launch(void* const* d_in, const int* in_sizes, int n_in,
                              void* d_out, int out_size, void* d_ws, size_t ws_size,
                              hipStream_t stream) {
  const float* x      = (const float*)d_in[0];
  const float* weight = (const float*)d_in[1];
  const float* bias   = (const float*)d_in[2];
  float* out = (float*)d_out;

  float* wsf      = (float*)d_ws;
  float* partials = wsf;                             // kAcc * kNB floats (transposed)
  float* statsg   = wsf + (size_t)kAcc * kNB;        // 152 reduced stats
  float* params   = statsg + kAcc;                   // 256 (D) + 16 (offset)

  fd_stats <<<kNB,  256, 0, stream>>>(x, partials);
  fd_reduce<<<kAcc, 256, 0, stream>>>(partials, statsg);
  fd_newton<<<1,    256, 0, stream>>>(statsg, params);
  fd_whiten<<<kP * kSplit, 256, 0, stream>>>(x, weight, bias, params, out);
}